// Round 3
// baseline (379.950 us; speedup 1.0000x reference)
//
#include <hip/hip_runtime.h>
#include <math.h>

#define T_LEN 100
#define K_LEN 25
#define DLAT 64
#define DHID 128

// ---------------------------------------------------------------------------
// buildW: W[c,i] = sum_t fc1_w[t]*conv_w[c,i-t+12];  b2[c] = conv_b[c]*S + fc1_b
// ---------------------------------------------------------------------------
__global__ __launch_bounds__(256) void buildW(const float* __restrict__ conv_w,
                                              const float* __restrict__ conv_b,
                                              const float* __restrict__ fc1_w,
                                              const float* __restrict__ fc1_b,
                                              float* __restrict__ W,
                                              float* __restrict__ b2) {
    int idx = blockIdx.x * 256 + threadIdx.x;
    if (idx < 64 * T_LEN) {
        int c = idx / T_LEN, i = idx % T_LEN;
        int t0 = i - 12 > 0 ? i - 12 : 0;
        int t1 = i + 12 < T_LEN - 1 ? i + 12 : T_LEN - 1;
        float acc = 0.f;
        for (int t = t0; t <= t1; ++t)
            acc += fc1_w[t] * conv_w[c * K_LEN + (i - t + 12)];
        W[idx] = acc;
    } else if (idx < 64 * T_LEN + 64) {
        int c = idx - 64 * T_LEN;
        float S = 0.f;
        for (int t = 0; t < T_LEN; ++t) S += fc1_w[t];
        b2[c] = conv_b[c] * S + fc1_b[0];
    }
}

// ---------------------------------------------------------------------------
// buildWc: fold the 64->128 projections through W:
//   j <  128: Wc[j,i] = sum_c rel_w[j,c]  * W[c,i];  bc[j] = b2·rel_w[j,:]
//   j >= 128: Wc[j,i] = sum_c root_w[j',c]* W[c,i];  bc[j] = b2·root_w[j',:]+rel_b[j']
// Then U[n,j] = sum_i x[n,i]*Wc[j,i] + bc[j] gives P (j<128) and R (j>=128).
// ---------------------------------------------------------------------------
__global__ __launch_bounds__(256) void buildWc(const float* __restrict__ W,
                                               const float* __restrict__ b2,
                                               const float* __restrict__ rel_w,
                                               const float* __restrict__ rel_b,
                                               const float* __restrict__ root_w,
                                               float* __restrict__ Wc,
                                               float* __restrict__ bc) {
    int idx = blockIdx.x * 256 + threadIdx.x;
    if (idx < 256 * T_LEN) {
        int j = idx / T_LEN, i = idx % T_LEN;
        const float* pw = (j < DHID) ? (rel_w + (size_t)j * DLAT)
                                     : (root_w + (size_t)(j - DHID) * DLAT);
        float acc = 0.f;
        for (int c = 0; c < DLAT; ++c) acc += pw[c] * W[c * T_LEN + i];
        Wc[idx] = acc;
    } else if (idx < 256 * T_LEN + 256) {
        int j = idx - 256 * T_LEN;
        const float* pw = (j < DHID) ? (rel_w + (size_t)j * DLAT)
                                     : (root_w + (size_t)(j - DHID) * DLAT);
        float acc = (j < DHID) ? 0.f : rel_b[j - DHID];
        for (int c = 0; c < DLAT; ++c) acc += pw[c] * b2[c];
        bc[j] = acc;
    }
}

// ---------------------------------------------------------------------------
// Phase B: per-graph 64x64 adjacency counts, stored as FLOAT (exact for small
// counts) so phaseCU can consume them via scalar loads without conversion.
// ---------------------------------------------------------------------------
__global__ void phaseB(const int* __restrict__ ei, float* __restrict__ adjF,
                       int E) {
    int e = blockIdx.x * blockDim.x + threadIdx.x;
    if (e >= E) return;
    int src = ei[e];
    int dst = ei[E + e];
    int g = dst >> 6;
    atomicAdd(&adjF[((size_t)g << 12) + ((unsigned)(dst & 63) << 6) + (unsigned)(src & 63)], 1.0f);
}

// ---------------------------------------------------------------------------
// phaseCU (one block = one graph, 512 threads = 8 waves):
//  Part 1: U[64 nodes][256 ch] = x_blk @ Wc^T + bc  -> LDS (row stride 257,
//          all LDS patterns are 2-way bank aliasing = free).
//          Wave w computes channels [32w,32w+32); lane = node; Wc via
//          wave-uniform s_load; x via per-lane float4 (L1-amortized x8 waves).
//  Part 2: out[n, j] = sum_s A[n,s]*U[s][j] + U[n][128+j]
//          Wave w owns n in [8w,8w+8); lane j-pair {lane, lane+64}; A rows
//          stream through scalar loads (float adj). 16 FMA per 2 LDS reads.
//  Epilogue: S/Q partial per wave -> LDS -> Sg/Qg[g, :].
// ---------------------------------------------------------------------------
__global__ __launch_bounds__(512, 4) void phaseCU(const float* __restrict__ x,
                                                  const float* __restrict__ Wc,
                                                  const float* __restrict__ bc,
                                                  const float* __restrict__ adjF,
                                                  float* __restrict__ Sg,
                                                  float* __restrict__ Qg) {
    __shared__ float lds[64 * 257 + 2 * 8 * 130];  // U + redS + redQ = 74 KB
    float* U = lds;
    float* redS = lds + 64 * 257;
    float* redQ = redS + 8 * 130;

    int tid = threadIdx.x;
    int lane = tid & 63;
    int w = __builtin_amdgcn_readfirstlane(tid >> 6);  // 0..7, wave-uniform
    int g = blockIdx.x;

    // ---- Part 1: U = x @ Wc^T + bc ----
    const float4* __restrict__ xp =
        (const float4*)(x + ((size_t)g * 64 + lane) * T_LEN);
    const float* __restrict__ Wb = Wc + (size_t)w * 32 * T_LEN;  // uniform
    float acc[32];
#pragma unroll
    for (int c = 0; c < 32; ++c) acc[c] = bc[w * 32 + c];
#pragma unroll
    for (int tq = 0; tq < T_LEN / 4; ++tq) {
        float4 xv = xp[tq];
#pragma unroll
        for (int c = 0; c < 32; ++c) {
            const float* wr = Wb + c * T_LEN + tq * 4;  // uniform -> s_load x4
            acc[c] += xv.x * wr[0] + xv.y * wr[1] + xv.z * wr[2] + xv.w * wr[3];
        }
    }
#pragma unroll
    for (int c4 = 0; c4 < 8; ++c4) {
        float4 o;
        o.x = acc[4 * c4 + 0]; o.y = acc[4 * c4 + 1];
        o.z = acc[4 * c4 + 2]; o.w = acc[4 * c4 + 3];
        *(float4*)&U[lane * 257 + w * 32 + 4 * c4] = o;
    }
    __syncthreads();

    // ---- Part 2: out = A @ P + R ----
    const float* __restrict__ Ag = adjF + ((size_t)g << 12);
    float acc2[16];  // [n8][jhalf]
#pragma unroll
    for (int i = 0; i < 16; ++i) acc2[i] = 0.f;

    for (int s0 = 0; s0 < 64; s0 += 8) {
        float a[8][8];
#pragma unroll
        for (int n8 = 0; n8 < 8; ++n8)
#pragma unroll
            for (int k = 0; k < 8; ++k)
                a[n8][k] = Ag[(8 * w + n8) * 64 + s0 + k];  // uniform -> s_load
#pragma unroll
        for (int k = 0; k < 8; ++k) {
            float v0 = U[(s0 + k) * 257 + lane];
            float v1 = U[(s0 + k) * 257 + 64 + lane];
#pragma unroll
            for (int n8 = 0; n8 < 8; ++n8) {
                acc2[2 * n8] += a[n8][k] * v0;
                acc2[2 * n8 + 1] += a[n8][k] * v1;
            }
        }
    }

    // ---- Epilogue: add R, square, reduce over n ----
    float sj0 = 0.f, qj0 = 0.f, sj1 = 0.f, qj1 = 0.f;
#pragma unroll
    for (int n8 = 0; n8 < 8; ++n8) {
        int n = 8 * w + n8;
        float o0 = acc2[2 * n8] + U[n * 257 + DHID + lane];
        float o1 = acc2[2 * n8 + 1] + U[n * 257 + DHID + 64 + lane];
        sj0 += o0; qj0 += o0 * o0;
        sj1 += o1; qj1 += o1 * o1;
    }
    redS[w * 130 + lane] = sj0;
    redS[w * 130 + 64 + lane] = sj1;
    redQ[w * 130 + lane] = qj0;
    redQ[w * 130 + 64 + lane] = qj1;
    __syncthreads();

    if (tid < DHID) {
        float S = 0.f, Q = 0.f;
#pragma unroll
        for (int w8 = 0; w8 < 8; ++w8) {
            S += redS[w8 * 130 + tid];
            Q += redQ[w8 * 130 + tid];
        }
        Sg[(size_t)g * DHID + tid] = S;
        Qg[(size_t)g * DHID + tid] = Q;
    }
}

// ---------------------------------------------------------------------------
// Phase D: BN stats per channel -> scale a[j], shift b[j]
// ---------------------------------------------------------------------------
__global__ __launch_bounds__(64) void phaseD(const float* __restrict__ Sg,
                                             const float* __restrict__ Qg,
                                             const float* __restrict__ gamma,
                                             const float* __restrict__ beta,
                                             float* __restrict__ ab,
                                             int G, int N) {
    int j = blockIdx.x;
    int t = threadIdx.x;
    float s = 0.f, q = 0.f;
    for (int g = t; g < G; g += 64) {
        s += Sg[g * DHID + j];
        q += Qg[g * DHID + j];
    }
#pragma unroll
    for (int off = 32; off; off >>= 1) {
        s += __shfl_xor(s, off);
        q += __shfl_xor(q, off);
    }
    if (t == 0) {
        float inv_n = 1.f / (float)N;
        float mean = s * inv_n;
        float var = q * inv_n - mean * mean;
        float a = rsqrtf(var + 1e-5f) * gamma[j];
        float b = beta[j] - mean * a;
        ab[j] = a;
        ab[DHID + j] = b;
    }
}

// ---------------------------------------------------------------------------
// Phase E: pooled = (a^2 Q + 2ab S)/64 + b^2 ; log(clamp) ; fc2 ; sigmoid
// ---------------------------------------------------------------------------
__global__ __launch_bounds__(128) void phaseE(const float* __restrict__ Sg,
                                              const float* __restrict__ Qg,
                                              const float* __restrict__ ab,
                                              const float* __restrict__ fc2_w,
                                              const float* __restrict__ fc2_b,
                                              float* __restrict__ y) {
    int g = blockIdx.x;
    int j = threadIdx.x;
    __shared__ float ps[DHID];
    float a = ab[j], b = ab[DHID + j];
    float S = Sg[g * DHID + j], Q = Qg[g * DHID + j];
    float pooled = (a * a * Q + 2.f * a * b * S) * (1.f / 64.f) + b * b;
    pooled = fmaxf(pooled, 1e-6f);
    ps[j] = logf(pooled);
    __syncthreads();
    if (j < 3) {
        float acc = fc2_b[j];
        for (int c = 0; c < DHID; ++c) acc += ps[c] * fc2_w[j * DHID + c];
        y[g * 3 + j] = 1.f / (1.f + expf(-acc));
    }
}

// ---------------------------------------------------------------------------
extern "C" void kernel_launch(void* const* d_in, const int* in_sizes, int n_in,
                              void* d_out, int out_size, void* d_ws, size_t ws_size,
                              hipStream_t stream) {
    const float* x      = (const float*)d_in[0];
    const int*   ei     = (const int*)d_in[1];
    const float* conv_w = (const float*)d_in[3];
    const float* conv_b = (const float*)d_in[4];
    const float* fc1_w  = (const float*)d_in[5];
    const float* fc1_b  = (const float*)d_in[6];
    const float* rel_w  = (const float*)d_in[7];
    const float* rel_b  = (const float*)d_in[8];
    const float* root_w = (const float*)d_in[9];
    const float* gamma  = (const float*)d_in[10];
    const float* beta   = (const float*)d_in[11];
    const float* fc2_w  = (const float*)d_in[12];
    const float* fc2_b  = (const float*)d_in[13];
    float* y = (float*)d_out;

    int N = in_sizes[2];       // 32768
    int E = in_sizes[1] / 2;   // 1048576
    int G = N / 64;            // 512

    float* ws   = (float*)d_ws;
    float* adjF = ws;                       // G*4096       (8 MB)
    float* Sg   = adjF + (size_t)G * 4096;  // G*128
    float* Qg   = Sg + (size_t)G * DHID;    // G*128
    float* ab   = Qg + (size_t)G * DHID;    // 256
    float* W    = ab + 2 * DHID;            // 64*100
    float* b2   = W + 64 * T_LEN;           // 64
    float* Wc   = b2 + 64;                  // 256*100
    float* bc   = Wc + 256 * T_LEN;         // 256

    hipMemsetAsync(adjF, 0, (size_t)G * 4096 * 4, stream);
    buildW<<<26, 256, 0, stream>>>(conv_w, conv_b, fc1_w, fc1_b, W, b2);
    buildWc<<<101, 256, 0, stream>>>(W, b2, rel_w, rel_b, root_w, Wc, bc);
    phaseB<<<(E + 255) / 256, 256, 0, stream>>>(ei, adjF, E);
    phaseCU<<<G, 512, 0, stream>>>(x, Wc, bc, adjF, Sg, Qg);
    phaseD<<<DHID, 64, 0, stream>>>(Sg, Qg, gamma, beta, ab, G, N);
    phaseE<<<G, DHID, 0, stream>>>(Sg, Qg, ab, fc2_w, fc2_b, y);
}